// Round 6
// baseline (235.033 us; speedup 1.0000x reference)
//
#include <hip/hip_runtime.h>

#define NTOK 32768      // 8*4096 tokens
#define HDIM 1024
#define NEXP 64
#define TK   8
#define NB   8
#define SEQ  4096

// ---- GEMM kernel geometry ----
#define MB    128               // tokens per block (halves B duplication vs 64)
#define KC    32                // K per chunk
#define NCH   (HDIM / KC)       // 32 chunks
#define NTHR  512               // 8 waves: wm=w>>1 (4x32 rows), wn=w&1 (2x32 experts)
#define NBLK  (NTOK / MB)       // 256 blocks

#define RING  5                 // 5-deep chunk ring, 3 chunks in flight
#define CH_A  16384             // A: 128 rows x 32 f32
#define CH_B  4096              // B hi (4KB); lo another 4KB
#define CHSZ  (CH_A + 2 * CH_B) // 24576; ring total 120KB LDS

typedef __attribute__((ext_vector_type(8))) short bf16x8;   // 8 bf16 = 4 VGPRs
typedef __attribute__((ext_vector_type(4))) float f32x4;

union BF8 { bf16x8 v; unsigned u[4]; };

__device__ inline unsigned f2bf(float x) {          // RTN-even fp32 -> bf16 bits
    unsigned u = __float_as_uint(x);
    return (u + 0x7FFFu + ((u >> 16) & 1u)) >> 16;
}

__device__ inline void split4(float4 v, unsigned* hp, unsigned* lp) {
    unsigned h0 = f2bf(v.x), h1 = f2bf(v.y), h2 = f2bf(v.z), h3 = f2bf(v.w);
    unsigned l0 = f2bf(v.x - __uint_as_float(h0 << 16));
    unsigned l1 = f2bf(v.y - __uint_as_float(h1 << 16));
    unsigned l2 = f2bf(v.z - __uint_as_float(h2 << 16));
    unsigned l3 = f2bf(v.w - __uint_as_float(h3 << 16));
    hp[0] = h0 | (h1 << 16); hp[1] = h2 | (h3 << 16);
    lp[0] = l0 | (l1 << 16); lp[1] = l2 | (l3 << 16);
}

// async global->LDS, 16B/lane; LDS dest = wave-uniform base + lane*16
__device__ __forceinline__ void gl16(const void* g, void* l) {
    __builtin_amdgcn_global_load_lds(
        (const __attribute__((address_space(1))) void*)g,
        (__attribute__((address_space(3))) void*)l, 16, 0, 0);
}

// One-time: split W into Dekker hi/lo bf16 in MFMA B-fragment order:
// slot(kk,n) (kk=K32-chunk 0..31, n=expert-16-group 0..3) = 64 lanes x 16B;
// lane l -> B[e=n*16+(l&15)][k=kk*32+(l>>4)*8 .. +8]. Chunk kk's 4 slots are
// contiguous 4KB at byte offset kk*4096 -> stageable with one gl16 per wave.
__global__ void wsplit(const float* __restrict__ w,
                       unsigned short* __restrict__ whi,
                       unsigned short* __restrict__ wlo)
{
    int T = blockIdx.x * 256 + threadIdx.x;     // 8192 threads = 128 slots x 64
    int slot = T >> 6, l = T & 63;
    int c = slot >> 3, s = (slot >> 2) & 1, n = slot & 3;
    int e = n * 16 + (l & 15);
    int k = c * 64 + s * 32 + (l >> 4) * 8;     // == (slot>>2)*32 + (l>>4)*8
    const float* src = w + (size_t)e * HDIM + k;
    float4 v0 = *(const float4*)(src);
    float4 v1 = *(const float4*)(src + 4);
    unsigned hp[4], lp[4];
    split4(v0, &hp[0], &lp[0]);
    split4(v1, &hp[2], &lp[2]);
    ((uint4*)whi)[T] = make_uint4(hp[0], hp[1], hp[2], hp[3]);
    ((uint4*)wlo)[T] = make_uint4(lp[0], lp[1], lp[2], lp[3]);
}

// R6: continuous-flow GEMM (T3/T4). R0-R5 all ran at dur = staged-bytes/3.3TB/s
// because every chunk ended in a full vmcnt(0)+barrier drain (__syncthreads
// semantics): pipeline depth 1, memory idle during each drain tail + compute.
// Now: 5-buffer ring, 3 chunks in flight, counted s_waitcnt vmcnt(9) + RAW
// s_barrier each chunk -- loads stream across barriers, vmcnt never hits 0
// until the epilogue. Hazard audit: stage at iter kk writes buf (kk+3)%5,
// last read at iter kk-2 -> 2 barriers of separation (write-after-read safe);
// barrier after each wave's own vmcnt wait makes chunk-kk data globally
// visible before any ds_read of it. 3 gl16/thread/chunk (A:2, B:1),
// wave-uniform -> exact counted waits. NO other vmem ops inside the loop.
__global__ __launch_bounds__(NTHR, 2) void moe_gemm(
    const float* __restrict__ hidden,           // [NTOK][HDIM] fp32
    const unsigned short* __restrict__ w2hi,    // frag-ordered bf16 hi
    const unsigned short* __restrict__ w2lo,    // frag-ordered bf16 lo
    float* __restrict__ logits)                 // [NTOK][NEXP] fp32
{
    __shared__ __align__(16) unsigned char smem[RING * CHSZ];

    const int tid   = threadIdx.x;
    const int w     = tid >> 6;         // 0..7
    const int l     = tid & 63;
    const int m     = l & 15;
    const int q     = l >> 4;
    const int wm    = w >> 1;           // token group: rows [32*wm, 32*wm+32)
    const int wn    = w & 1;            // expert group: cols [32*wn, 32*wn+32)
    const int wbase = tid & 448;        // w*64
    const size_t t0 = (size_t)blockIdx.x * MB;

    const unsigned short* bsrc = (w < 4) ? w2hi : w2lo;   // wave-split B staging
    const int w4   = w & 3;
    const int bDst = CH_A + (w >> 2) * CH_B + w4 * 1024;  // wave-uniform LDS dest

    // stage chunk kk into ring buffer nb: A XOR-swizzled (slot p^=(r&7) within
    // each 128B row), B linear fragment slots. 3 gl16 per thread.
    auto stage = [&](int kk, unsigned char* nb) {
#pragma unroll
        for (int i = 0; i < 2; ++i) {
            int g  = i * NTHR + tid;            // 16B slot 0..1023
            int r  = g >> 3;                    // row 0..127
            int sp = (g & 7) ^ (r & 7);         // inverse swizzle on source
            gl16(hidden + (t0 + r) * HDIM + kk * KC + sp * 4,
                 nb + (size_t)(i * NTHR + wbase) * 16);
        }
        gl16(bsrc + (size_t)kk * 2048 + (size_t)(w4 * 64 + l) * 8,
             nb + bDst);
    };

    f32x4 acc[2][2];
#pragma unroll
    for (int mt = 0; mt < 2; ++mt)
#pragma unroll
        for (int n = 0; n < 2; ++n) acc[mt][n] = (f32x4)0.f;

    // prologue: 3 chunks in flight
    stage(0, smem);
    stage(1, smem + CHSZ);
    stage(2, smem + 2 * CHSZ);

    int bufR = 0, bufW = 3;
    for (int kk = 0; kk < NCH; ++kk) {
        if (kk + 3 < NCH) {
            stage(kk + 3, smem + bufW * CHSZ);
            bufW = (bufW == RING - 1) ? 0 : bufW + 1;
        }
        // counted wait: chunk kk's 3 loads are the oldest; keep the rest in flight
        if      (kk + 3 <  NCH) asm volatile("s_waitcnt vmcnt(9)" ::: "memory");
        else if (kk + 3 == NCH) asm volatile("s_waitcnt vmcnt(6)" ::: "memory");
        else if (kk + 2 == NCH) asm volatile("s_waitcnt vmcnt(3)" ::: "memory");
        else                    asm volatile("s_waitcnt vmcnt(0)" ::: "memory");
        __builtin_amdgcn_s_barrier();           // raw: no vmcnt(0) drain
        __builtin_amdgcn_sched_barrier(0);      // pin: nothing moves above

        const unsigned char* Ab = smem + bufR * CHSZ;
        bufR = (bufR == RING - 1) ? 0 : bufR + 1;

        // B fragments (conflict-free: 16B/lane contiguous)
        bf16x8 bh[2], bl[2];
#pragma unroll
        for (int n = 0; n < 2; ++n) {
            int off = CH_A + (wn * 2 + n) * 1024 + l * 16;
            bh[n] = *(const bf16x8*)(Ab + off);
            bl[n] = *(const bf16x8*)(Ab + CH_B + off);
        }

        // A fragments + bf16x3 MFMA; k-order sequential (matches R0 ordering)
#pragma unroll
        for (int mt = 0; mt < 2; ++mt) {
            int r   = wm * 32 + mt * 16 + m;            // r&7 == m&7
            int sp0 = (q * 2)     ^ (r & 7);
            int sp1 = (q * 2 + 1) ^ (r & 7);
            float4 a0 = *(const float4*)(Ab + ((size_t)r * 8 + sp0) * 16);
            float4 a1 = *(const float4*)(Ab + ((size_t)r * 8 + sp1) * 16);
            BF8 ah, al;
            split4(a0, &ah.u[0], &al.u[0]);
            split4(a1, &ah.u[2], &al.u[2]);
#pragma unroll
            for (int n = 0; n < 2; ++n) {
                acc[mt][n] = __builtin_amdgcn_mfma_f32_16x16x32_bf16(ah.v, bh[n], acc[mt][n], 0, 0, 0);
                acc[mt][n] = __builtin_amdgcn_mfma_f32_16x16x32_bf16(al.v, bh[n], acc[mt][n], 0, 0, 0);
                acc[mt][n] = __builtin_amdgcn_mfma_f32_16x16x32_bf16(ah.v, bl[n], acc[mt][n], 0, 0, 0);
            }
        }
    }

    // epilogue: C/D layout row=(lane>>4)*4+reg (token), col=lane&15 (expert)
#pragma unroll
    for (int mt = 0; mt < 2; ++mt)
#pragma unroll
        for (int n = 0; n < 2; ++n)
#pragma unroll
            for (int r = 0; r < 4; ++r)
                logits[(t0 + wm * 32 + mt * 16 + q * 4 + r) * NEXP
                       + wn * 32 + n * 16 + m] = acc[mt][n][r];
}

// Phase 2 standalone (ablation + proven R5 code): 64 tokens/block, 8 waves.
__global__ __launch_bounds__(512, 4) void moe_gate(
    const float* __restrict__ logits,
    float* __restrict__ out,
    float* __restrict__ ws)
{
    __shared__ float sLog[64 * 66];
    __shared__ float mxArr[64];
    __shared__ float smSum[NEXP];
    __shared__ int   hist[NEXP];

    const int tid = threadIdx.x;
    const int w   = tid >> 6;
    const int l   = tid & 63;
    const int t0  = blockIdx.x * 64;

    if (tid < NEXP) { smSum[tid] = 0.f; hist[tid] = 0; }

    // load 64x64 logits -> sLog (stride 66)
    const float4* src = (const float4*)(logits + (size_t)t0 * NEXP);
#pragma unroll
    for (int j = 0; j < 2; ++j) {
        int g = j * 512 + tid;          // float4 index 0..1023
        float4 v = src[g];
        int r = g >> 4, c = (g & 15) * 4;
        float* d = &sLog[r * 66 + c];
        d[0] = v.x; d[1] = v.y; d[2] = v.z; d[3] = v.w;
    }
    __syncthreads();

    // ---- phase 2a: softmax stats (lane = expert); wave w: tokens [8w, 8w+8)
    float mxKeep = 0.f;
    float regSm = 0.f;
    for (int j = 0; j < 8; ++j) {
        int t = w * 8 + j;
        float x = sLog[t * 66 + l];
        float mx = x;
#pragma unroll
        for (int off = 32; off; off >>= 1) mx = fmaxf(mx, __shfl_xor(mx, off));
        float p = __expf(x - mx);
        float sd = p;
#pragma unroll
        for (int off = 32; off; off >>= 1) sd += __shfl_xor(sd, off);
        regSm += p / sd;
        if (l == 0) mxArr[t] = mx;
        (void)mxKeep;
    }
    atomicAdd(&smSum[l], regSm);
    __syncthreads();

    // ---- phase 2b: top-8 per token, lane = token (wave 0 only) ----
    if (w == 0) {
        const float mx = mxArr[l];
        unsigned long long s8[TK];
#pragma unroll
        for (int j = 0; j < TK; ++j) s8[j] = 0ull;
        for (int e = 0; e < NEXP; ++e) {
            float x = sLog[l * 66 + e];
            unsigned u = __float_as_uint(x);
            unsigned k32 = (u & 0x80000000u) ? ~u : (u | 0x80000000u);
            unsigned long long key = ((unsigned long long)k32 << 6)
                                   | (unsigned long long)(63 - e);
            if (key > s8[TK - 1]) {
#pragma unroll
                for (int j = 0; j < TK; ++j) {
                    unsigned long long hi = s8[j] > key ? s8[j] : key;
                    key = s8[j] > key ? key : s8[j];
                    s8[j] = hi;
                }
            }
        }
        float ev[TK]; int ei[TK]; float sum = 0.f;
#pragma unroll
        for (int j = 0; j < TK; ++j) {
            unsigned k32 = (unsigned)(s8[j] >> 6);
            unsigned u = (k32 >> 31) ? (k32 ^ 0x80000000u) : ~k32;
            ev[j] = __expf(__uint_as_float(u) - mx);
            sum += ev[j];
            ei[j] = 63 - (int)(s8[j] & 63ull);
        }
        int t = t0 + l;
        float4 i0 = make_float4((float)ei[0], (float)ei[1], (float)ei[2], (float)ei[3]);
        float4 i1 = make_float4((float)ei[4], (float)ei[5], (float)ei[6], (float)ei[7]);
        *(float4*)(out + (size_t)t * TK)     = i0;
        *(float4*)(out + (size_t)t * TK + 4) = i1;
        float rs = 1.f / (sum + 1e-20f);
        float4 w0 = make_float4(ev[0] * rs, ev[1] * rs, ev[2] * rs, ev[3] * rs);
        float4 w1 = make_float4(ev[4] * rs, ev[5] * rs, ev[6] * rs, ev[7] * rs);
        *(float4*)(out + (size_t)NTOK * TK + (size_t)t * TK)     = w0;
        *(float4*)(out + (size_t)NTOK * TK + (size_t)t * TK + 4) = w1;
#pragma unroll
        for (int j = 0; j < TK; ++j) atomicAdd(&hist[ei[j]], 1);
    }
    __syncthreads();

    if (tid < NEXP) {
        int b = blockIdx.x >> 6;            // 64 gate-blocks per batch element
        atomicAdd(&ws[b * NEXP + tid], (float)hist[tid]);
        atomicAdd(&ws[NB * NEXP + b * NEXP + tid], smSum[tid]);
    }
}

__global__ void moe_finalize(const float* __restrict__ ws, float* __restrict__ out)
{
    int e = threadIdx.x;   // 64 threads
    float cnt = 0.f, accv = 0.f;
#pragma unroll
    for (int b = 0; b < NB; ++b) {
        float c  = ws[b * NEXP + e];
        float sm = ws[NB * NEXP + b * NEXP + e];
        cnt += c;
        accv += c * sm;
    }
    out[(size_t)NTOK * TK * 2 + 1 + e] = cnt;   // expert_counts (as float)
#pragma unroll
    for (int off = 32; off; off >>= 1) accv += __shfl_xor(accv, off);
    if (e == 0) {
        float aux = 0.01f * accv * ((float)NEXP / ((float)SEQ * (float)TK))
                    / (float)SEQ / (float)NB;
        out[(size_t)NTOK * TK * 2] = aux;
    }
}

extern "C" void kernel_launch(void* const* d_in, const int* in_sizes, int n_in,
                              void* d_out, int out_size, void* d_ws, size_t ws_size,
                              hipStream_t stream)
{
    const float* hidden = (const float*)d_in[0];
    const float* weight = (const float*)d_in[1];
    float* out  = (float*)d_out;
    float* wsf  = (float*)d_ws;
    unsigned short* w2hi = (unsigned short*)(wsf + 2 * NB * NEXP);      // +4KB
    unsigned short* w2lo = w2hi + NEXP * HDIM;                          // +128KB
    float* logits = (float*)(w2lo + NEXP * HDIM);                       // +128KB, 8MB

    hipMemsetAsync(d_ws, 0, 2 * NB * NEXP * sizeof(float), stream);
    wsplit<<<32, 256, 0, stream>>>(weight, w2hi, w2lo);
    moe_gemm<<<NBLK, NTHR, 0, stream>>>(hidden, w2hi, w2lo, logits);
    moe_gate<<<NTOK / 64, 512, 0, stream>>>(logits, out, wsf);
    moe_finalize<<<1, 64, 0, stream>>>(wsf, out);
}